// Round 9
// baseline (362.079 us; speedup 1.0000x reference)
//
#include <hip/hip_runtime.h>

// ---------------- problem constants ----------------
constexpr int Bv = 2, Cv = 64, Hv = 192, Wv = 192;
constexpr int Hp = 194, Wp = 194;
constexpr int PLANE = Hp * Wp;            // 37636
constexpr int NCIN = 65;                  // 64 x-channels + depth
constexpr int Lv = Hv * Wv;               // 36864
constexpr int XP_SZ  = Bv * NCIN * PLANE; // padded input elements (bf16)

// patch geometry (per 32-px tile): rows pr0..pr0+5, cols pc0..pc0+39
constexpr int PR = 6, PC = 40;            // rows x cols (u16)
constexpr int CSTR = 242;                 // channel stride in u16 (bank spread)

typedef __attribute__((ext_vector_type(8))) short short8;
typedef __attribute__((ext_vector_type(4))) float f32x4;
typedef unsigned short u16;

__device__ __forceinline__ u16 f2b(float v) {
  unsigned u = __float_as_uint(v);
  u = (u + 0x7FFFu + ((u >> 16) & 1u)) >> 16;   // RNE
  return (u16)u;
}
__device__ __forceinline__ float b2f(u16 u) {
  return __uint_as_float(((unsigned)u) << 16);
}

// ---------------- K0: build padded bf16 input ----------------
__global__ __launch_bounds__(256) void pad_kernel(
    const float* __restrict__ x, const float* __restrict__ depth,
    u16* __restrict__ xp) {
  for (int idx = blockIdx.x * blockDim.x + threadIdx.x; idx < XP_SZ;
       idx += gridDim.x * blockDim.x) {
    int p  = idx % PLANE;
    int bc = idx / PLANE;
    int c  = bc % NCIN;
    int b  = bc / NCIN;
    int ph = p / Wp, pw = p % Wp;
    float v = 0.f;
    if (ph >= 1 && ph <= Hv && pw >= 1 && pw <= Wv) {
      int ih = ph - 1, iw = pw - 1;
      v = (c < Cv) ? x[((b * Cv + c) * Hv + ih) * Wv + iw]
                   : depth[(b * Hv + ih) * Wv + iw];
    }
    xp[idx] = f2b(v);
  }
}

// ---------------- K0b: prep weights -> bf16 ----------------
// Wb[o][t*64+c] = bf16(W[o][c*9+t])   (main GEMM A, t-major K)
// Woffb[o][k]   = bf16(wo[o*585+k]) for o<18,k<585 else 0  (offset A)
__global__ __launch_bounds__(256) void prep_kernel(
    const float* __restrict__ Wg, const float* __restrict__ wo,
    u16* __restrict__ Wb, u16* __restrict__ Woffb) {
  int n = blockIdx.x * 256 + threadIdx.x;
  if (n < 64 * 576) {
    int o = n / 576, r = n % 576;
    int t = r >> 6, c = r & 63;
    Wb[n] = f2b(Wg[o * 576 + c * 9 + t]);
  }
  if (n < 32 * 640) {
    int o = n / 640, k = n % 640;
    Woffb[n] = (o < 18 && k < 585) ? f2b(wo[o * 585 + k]) : (u16)0;
  }
}

// ---------------- K1: patch-based fused kernel ----------------
// Block = 32 px (one row segment). Phases:
//  0: stage 65x6x40 bf16 patch into LDS (coalesced dwords)  [1 barrier]
//  1: offset GEMM, B-frags read directly from patch          [1 barrier]
//  2: meta -> s_mi (patch-relative or ~global) + s_w4        [1 barrier]
//  3: main GEMM, B-frags lerped directly from patch, no barriers
__global__ __launch_bounds__(256, 4) void fused_kernel(
    const u16* __restrict__ xp, const u16* __restrict__ Wb,
    const u16* __restrict__ Woffb, const float* __restrict__ bias,
    float* __restrict__ out) {
  int bid = blockIdx.x;
  int swz = (bid & 7) * 288 + (bid >> 3);   // 2304 % 8 == 0, bijective
  int b   = swz / 1152;
  int l0  = (swz % 1152) * 32;
  int oh  = l0 / 192;
  int ow0 = l0 - oh * 192;                  // multiple of 32
  int pr0 = min(max(oh - 1, 0), 188);
  int pc0 = min(max(ow0 - 2, 0), 154);      // even

  __shared__ u16    s_patch[NCIN * CSTR];   // 31460 B
  __shared__ float  s_off[18][32];
  __shared__ int    s_mi[288];
  __shared__ float4 s_w4[288];

  int tid  = threadIdx.x;
  int lane = tid & 63;
  int iq   = __builtin_amdgcn_readfirstlane(tid >> 6);  // wave 0..3
  const u16* xbb = xp + (size_t)(b * NCIN) * PLANE;

  // ================= Phase 0: patch staging =================
  {
    const u16* src0 = xbb + pr0 * Wp + pc0;
    for (int e = tid; e < NCIN * PR * 20; e += 256) {
      int c   = e / (PR * 20);
      int rem = e - c * (PR * 20);
      int r = rem / 20, seg = rem - r * 20;
      unsigned v = *(const unsigned*)(src0 + c * PLANE + r * Wp + seg * 2);
      *(unsigned*)&s_patch[c * CSTR + r * PC + seg * 2] = v;
    }
  }
  __syncthreads();

  int mo = iq >> 1;      // o-tile pair index
  int np = iq & 1;       // px half
  int cl = lane & 15;
  int kgrp = lane >> 4;

  // ================= Phase 1: offset GEMM =================
  {
    f32x4 oacc = (f32x4)0.f;
    for (int ch = 0; ch < 10; ++ch) {
#pragma unroll
      for (int ks = 0; ks < 2; ++ks) {
        int ko = ch * 64 + ks * 32 + (kgrp << 3);
        short8 bb;
#pragma unroll
        for (int j = 0; j < 8; ++j) {
          int k = ko + j;
          int c = (k * 7282) >> 16;        // k/9 exact (k<3640)
          int t = k - c * 9;
          c = min(c, 64);                  // pad-k -> depth plane (A is 0)
          int th = (t * 11) >> 5;          // t/3
          int tw = t - 3 * th;
          int rr = oh + th - pr0;
          int cc = ow0 + np * 16 + cl + tw - pc0;
          bb[j] = (short)s_patch[c * CSTR + rr * PC + cc];
        }
        short8 a = *(const short8*)&Woffb[(mo * 16 + cl) * 640 + ko];
        oacc = __builtin_amdgcn_mfma_f32_16x16x32_bf16(a, bb, oacc, 0, 0, 0);
      }
    }
    int rr = kgrp;
#pragma unroll
    for (int j = 0; j < 4; ++j) {
      int o = mo * 16 + rr * 4 + j;
      if (o < 18) s_off[o][np * 16 + cl] = oacc[j];
    }
  }
  __syncthreads();

  // ================= Phase 2: meta =================
  for (int e = tid; e < 288; e += 256) {
    int t = e >> 5, pxl = e & 31;
    int ow = ow0 + pxl;
    float ox = s_off[t][pxl] + bias[t];
    float oy = s_off[9 + t][pxl] + bias[9 + t];
    int th = (t * 11) >> 5;
    int tw = t - 3 * th;
    float cx = (float)(oh + th) + ox;       // base+delta+offset (padded)
    float cy = (float)(ow + tw) + oy;
    cx = fminf(fmaxf(cx, 0.f), 193.f);
    cy = fminf(fmaxf(cy, 0.f), 193.f);
    int tlx = min((int)cx, 192);
    int tly = min((int)cy, 192);
    float fx = cx - (float)tlx, fy = cy - (float)tly;
    float ax = 1.f - fx, ay = 1.f - fy;
    int prr = tlx - pr0, pcc = tly - pc0;
    int pmi;
    if (prr >= 0 && prr <= PR - 2 && pcc >= 0 && pcc <= PC - 2)
      pmi = prr * PC + pcc;                 // patch-relative
    else
      pmi = ~(tlx * Wp + tly);              // fallback: global (negative)
    s_mi[e] = pmi;
    s_w4[e] = make_float4(ax * ay, ax * fy, fx * ay, fx * fy);
  }
  __syncthreads();

  // ================= Phase 3: main GEMM (barrier-free) =================
  {
    int arow0 = (mo * 32 + cl) * 576;
    int arow1 = arow0 + 16 * 576;
    int mypx  = np * 16 + cl;
    f32x4 acc0 = (f32x4)0.f, acc1 = (f32x4)0.f;

    for (int ch = 0; ch < 9; ++ch) {
      int    pmi = s_mi[ch * 32 + mypx];
      float4 w   = s_w4[ch * 32 + mypx];
#pragma unroll
      for (int ks = 0; ks < 2; ++ks) {
        int cb = ks * 32 + (kgrp << 3);     // channel-octet base
        short8 bb;
        if (pmi >= 0) {
          const u16* p = &s_patch[cb * CSTR + pmi];
#pragma unroll
          for (int j = 0; j < 8; ++j) {
            const u16* q = p + j * CSTR;
            float v = w.x * b2f(q[0])  + w.y * b2f(q[1]) +
                      w.z * b2f(q[PC]) + w.w * b2f(q[PC + 1]);
            bb[j] = (short)(__float_as_uint(v) >> 16);   // truncate pack
          }
        } else {
          int gmi = ~pmi;
          const u16* p = xbb + (size_t)cb * PLANE + gmi;
#pragma unroll
          for (int j = 0; j < 8; ++j) {
            const u16* q = p + (size_t)j * PLANE;
            float v = w.x * b2f(q[0])  + w.y * b2f(q[1]) +
                      w.z * b2f(q[Wp]) + w.w * b2f(q[Wp + 1]);
            bb[j] = (short)(__float_as_uint(v) >> 16);
          }
        }
        int k = ch * 64 + cb;
        short8 a0 = *(const short8*)&Wb[arow0 + k];
        short8 a1 = *(const short8*)&Wb[arow1 + k];
        acc0 = __builtin_amdgcn_mfma_f32_16x16x32_bf16(a0, bb, acc0, 0, 0, 0);
        acc1 = __builtin_amdgcn_mfma_f32_16x16x32_bf16(a1, bb, acc1, 0, 0, 0);
      }
    }

    // epilogue: D row=(lane>>4)*4+j, col=lane&15
#pragma unroll
    for (int j = 0; j < 4; ++j) {
      int o = mo * 32 + kgrp * 4 + j;
      out[(size_t)(b * Cv + o) * Lv + l0 + mypx]      = acc0[j];
      out[(size_t)(b * Cv + o + 16) * Lv + l0 + mypx] = acc1[j];
    }
  }
}

// ---------------- launch ----------------
extern "C" void kernel_launch(void* const* d_in, const int* in_sizes, int n_in,
                              void* d_out, int out_size, void* d_ws, size_t ws_size,
                              hipStream_t stream) {
  const float* x     = (const float*)d_in[0];
  const float* depth = (const float*)d_in[1];
  const float* wo    = (const float*)d_in[2];
  const float* bias  = (const float*)d_in[3];
  const float* wgt   = (const float*)d_in[4];
  float* out = (float*)d_out;

  u16* xp16  = (u16*)d_ws;                          // XP_SZ u16
  u16* Wb    = xp16 + XP_SZ;                        // 64*576
  u16* Woffb = Wb + 64 * 576;                       // 32*640

  pad_kernel<<<2048, 256, 0, stream>>>(x, depth, xp16);
  prep_kernel<<<144, 256, 0, stream>>>(wgt, wo, Wb, Woffb);
  fused_kernel<<<2304, 256, 0, stream>>>(xp16, Wb, Woffb, bias, out);
}

// Round 10
// 221.556 us; speedup vs baseline: 1.6343x; 1.6343x over previous
//
#include <hip/hip_runtime.h>

// ---------------- problem constants ----------------
constexpr int Bv = 2, Cv = 64, Hv = 192, Wv = 192;
constexpr int Hp = 194, Wp = 194;
constexpr int PLANE = Hp * Wp;            // 37636
constexpr int Lv = Hv * Wv;               // 36864

typedef __attribute__((ext_vector_type(8))) short short8;
typedef __attribute__((ext_vector_type(4))) float f32x4;
typedef unsigned short u16;

__device__ __forceinline__ u16 f2b(float v) {
  unsigned u = __float_as_uint(v);
  u = (u + 0x7FFFu + ((u >> 16) & 1u)) >> 16;   // RNE
  return (u16)u;
}
__device__ __forceinline__ float b2f(u16 u) {
  return __uint_as_float(((unsigned)u) << 16);
}

// ---------------- K0: padded CHANNEL-LAST bf16 input + depth plane -------
// xclp[b][ph][pw][c64] (c contiguous!), dpad[b][ph][pw]
__global__ __launch_bounds__(256) void pad_kernel(
    const float* __restrict__ x, const float* __restrict__ depth,
    u16* __restrict__ xclp, u16* __restrict__ dpad) {
  int blk  = blockIdx.x;              // 776 = Bv * Hp * 2
  int half = blk & 1;
  int rb   = blk >> 1;
  int b  = rb / Hp, ph = rb % Hp;
  int ih = ph - 1;
  bool rowok = (ih >= 0) && (ih < Hv);
  int pw0 = half * 97;                // 97 + 97 = 194
  u16* orow = xclp + ((size_t)b * PLANE + (size_t)ph * Wp) * 64;

  for (int e = threadIdx.x; e < 97 * 8; e += 256) {
    int pw  = pw0 + (e >> 3);
    int oct = e & 7;
    int iw  = pw - 1;
    bool ok = rowok && iw >= 0 && iw < Wv;
    short8 hv;
#pragma unroll
    for (int j = 0; j < 8; ++j) {
      int c = oct * 8 + j;
      float v = ok ? x[(((size_t)b * Cv + c) * Hv + ih) * Wv + iw] : 0.f;
      hv[j] = (short)f2b(v);
    }
    *(short8*)&orow[(size_t)pw * 64 + oct * 8] = hv;
  }
  for (int e = threadIdx.x; e < 97; e += 256) {
    int pw = pw0 + e;
    int iw = pw - 1;
    float v = (rowok && iw >= 0 && iw < Wv)
                  ? depth[((size_t)b * Hv + ih) * Wv + iw] : 0.f;
    dpad[(size_t)b * PLANE + ph * Wp + pw] = f2b(v);
  }
}

// ---------------- K0b: prep weights -> bf16, t-major K -------------------
// Wb[o][t*64+c]   = bf16(W[o][c*9+t])          (main GEMM A)
// Woxb[o][t*64+c] = bf16(wo[o*585 + c*9 + t])  o<18 else 0 (offset A, x-part)
__global__ __launch_bounds__(256) void prep_kernel(
    const float* __restrict__ Wg, const float* __restrict__ wo,
    u16* __restrict__ Wb, u16* __restrict__ Woxb) {
  int n = blockIdx.x * 256 + threadIdx.x;
  if (n < 64 * 576) {
    int o = n / 576, r = n % 576;
    int t = r >> 6, c = r & 63;
    Wb[n] = f2b(Wg[o * 576 + c * 9 + t]);
  }
  if (n < 32 * 576) {
    int o = n / 576, r = n % 576;
    int t = r >> 6, c = r & 63;
    Woxb[n] = (o < 18) ? f2b(wo[o * 585 + c * 9 + t]) : (u16)0;
  }
}

// ---------------- K1: fused kernel, barrier-free K-loops -----------------
// Block = 32 px x 64 out-ch, 4 waves (mw x nw = 2x2 of 16x16 / 32x16 tiles).
// B-fragments built per-lane from channel-last global: no LDS for B.
__global__ __launch_bounds__(256) void fused_kernel(
    const u16* __restrict__ xclp, const u16* __restrict__ dpad,
    const u16* __restrict__ Wb, const u16* __restrict__ Woxb,
    const float* __restrict__ wo, const float* __restrict__ bias,
    float* __restrict__ out) {
  int bid = blockIdx.x;
  int swz = (bid & 7) * 288 + (bid >> 3);   // 2304 % 8 == 0, bijective
  int b   = swz / 1152;
  int l0  = (swz % 1152) * 32;
  int oh  = l0 / 192;                       // all 32 px share the row
  int ow0 = l0 - oh * 192;

  __shared__ float  s_off[18][32];
  __shared__ int    s_mi[288];
  __shared__ float4 s_w4[288];
  __shared__ float  s_drow[3][40];          // depth rows oh..oh+2
  __shared__ float  s_wd[18][9];            // depth-channel offset weights

  int tid  = threadIdx.x;
  int lane = tid & 63;
  int iq   = __builtin_amdgcn_readfirstlane(tid >> 6);  // wave 0..3
  int mw   = iq >> 1;                       // o-tile pair
  int nw   = iq & 1;                        // px half
  int cl   = lane & 15;
  int kgrp = lane >> 4;
  int px16 = nw * 16 + cl;                  // this lane's pixel

  const u16* xclb = xclp + (size_t)b * PLANE * 64;

  // ---- prologue staging: depth row + depth weights ----
  for (int e = tid; e < 102; e += 256) {
    int r = e / 34, cc = e - r * 34;
    s_drow[r][cc] = b2f(dpad[(size_t)b * PLANE + (oh + r) * Wp + ow0 + cc]);
  }
  for (int e = tid; e < 162; e += 256) {
    int o = e / 9, tt = e - o * 9;
    s_wd[o][tt] = wo[o * 585 + 576 + tt];   // weight_offset[o][c=64][tap]
  }

  // ================= Phase 1: offset GEMM (x-part), barrier-free ========
  {
    f32x4 oacc = (f32x4)0.f;
#pragma unroll
    for (int t = 0; t < 9; ++t) {
      int th = t / 3, tw = t % 3;
      size_t base = ((size_t)(oh + th) * Wp + ow0 + px16 + tw) * 64;
#pragma unroll
      for (int ks = 0; ks < 2; ++ks) {
        int oct = ks * 4 + kgrp;
        short8 bb = *(const short8*)&xclb[base + oct * 8];
        short8 a  = *(const short8*)&Woxb[(mw * 16 + cl) * 576 +
                                          t * 64 + ks * 32 + kgrp * 8];
        oacc = __builtin_amdgcn_mfma_f32_16x16x32_bf16(a, bb, oacc, 0, 0, 0);
      }
    }
#pragma unroll
    for (int j = 0; j < 4; ++j) {
      int o = mw * 16 + kgrp * 4 + j;
      if (o < 18) s_off[o][px16] = oacc[j];
    }
  }
  __syncthreads();

  // ================= Phase 2: meta (adds depth part + bias) =============
  for (int e = tid; e < 288; e += 256) {
    int t = e >> 5, pxl = e & 31;
    int ow = ow0 + pxl;
    float ox = s_off[t][pxl] + bias[t];
    float oy = s_off[9 + t][pxl] + bias[9 + t];
#pragma unroll
    for (int tt = 0; tt < 9; ++tt) {
      float dv = s_drow[tt / 3][pxl + tt % 3];
      ox += s_wd[t][tt] * dv;
      oy += s_wd[9 + t][tt] * dv;
    }
    int th = t / 3, tw = t % 3;
    float cx = (float)(oh + th) + ox;       // base+delta+offset (padded)
    float cy = (float)(ow + tw) + oy;
    cx = fminf(fmaxf(cx, 0.f), 193.f);
    cy = fminf(fmaxf(cy, 0.f), 193.f);
    int tlx = min((int)cx, 192);
    int tly = min((int)cy, 192);
    float fx = cx - (float)tlx, fy = cy - (float)tly;
    float ax = 1.f - fx, ay = 1.f - fy;
    s_mi[e] = tlx * Wp + tly;
    s_w4[e] = make_float4(ax * ay, ax * fy, fx * ay, fx * fy);
  }
  __syncthreads();

  // ================= Phase 3: main GEMM, barrier-free ===================
  {
    int arow0 = (mw * 32 + cl) * 576;
    int arow1 = arow0 + 16 * 576;
    f32x4 acc0 = (f32x4)0.f, acc1 = (f32x4)0.f;

#pragma unroll
    for (int t = 0; t < 9; ++t) {
      int    pmi = s_mi[t * 32 + px16];
      float4 w   = s_w4[t * 32 + px16];
      size_t p00 = (size_t)pmi * 64;
#pragma unroll
      for (int ks = 0; ks < 2; ++ks) {
        int oct = ks * 4 + kgrp;
        const u16* p = &xclb[p00 + oct * 8];
        short8 c00 = *(const short8*)(p);
        short8 c01 = *(const short8*)(p + 64);
        short8 c10 = *(const short8*)(p + Wp * 64);
        short8 c11 = *(const short8*)(p + Wp * 64 + 64);
        short8 bb;
#pragma unroll
        for (int j = 0; j < 8; ++j) {
          float v = w.x * b2f((u16)c00[j]) + w.y * b2f((u16)c01[j]) +
                    w.z * b2f((u16)c10[j]) + w.w * b2f((u16)c11[j]);
          bb[j] = (short)f2b(v);
        }
        int k = t * 64 + ks * 32 + kgrp * 8;
        short8 a0 = *(const short8*)&Wb[arow0 + k];
        short8 a1 = *(const short8*)&Wb[arow1 + k];
        acc0 = __builtin_amdgcn_mfma_f32_16x16x32_bf16(a0, bb, acc0, 0, 0, 0);
        acc1 = __builtin_amdgcn_mfma_f32_16x16x32_bf16(a1, bb, acc1, 0, 0, 0);
      }
    }

    // epilogue: D row=(lane>>4)*4+j, col=lane&15
#pragma unroll
    for (int j = 0; j < 4; ++j) {
      int o = mw * 32 + kgrp * 4 + j;
      out[(size_t)(b * Cv + o) * Lv + l0 + px16]      = acc0[j];
      out[(size_t)(b * Cv + o + 16) * Lv + l0 + px16] = acc1[j];
    }
  }
}

// ---------------- launch ----------------
extern "C" void kernel_launch(void* const* d_in, const int* in_sizes, int n_in,
                              void* d_out, int out_size, void* d_ws, size_t ws_size,
                              hipStream_t stream) {
  const float* x     = (const float*)d_in[0];
  const float* depth = (const float*)d_in[1];
  const float* wo    = (const float*)d_in[2];
  const float* bias  = (const float*)d_in[3];
  const float* wgt   = (const float*)d_in[4];
  float* out = (float*)d_out;

  u16* xclp = (u16*)d_ws;                           // Bv*PLANE*64
  u16* dpad = xclp + (size_t)Bv * PLANE * 64;       // Bv*PLANE
  u16* Wb   = dpad + (size_t)Bv * PLANE;            // 64*576
  u16* Woxb = Wb + 64 * 576;                        // 32*576

  pad_kernel<<<776, 256, 0, stream>>>(x, depth, xclp, dpad);
  prep_kernel<<<144, 256, 0, stream>>>(wgt, wo, Wb, Woxb);
  fused_kernel<<<2304, 256, 0, stream>>>(xclp, dpad, Wb, Woxb, wo, bias, out);
}